// Round 9
// baseline (445.203 us; speedup 1.0000x reference)
//
#include <hip/hip_runtime.h>

typedef unsigned short u16;
typedef __attribute__((ext_vector_type(8))) short bf16x8;
typedef __attribute__((ext_vector_type(4))) float f32x4;

// B=4, C=Cin=256, H=W=128.
// Activations: staging-ready global layout [b][h][half(ci>>7)][w][256B], each
// 256B half-row XOR-swizzled by key ((w+1)&7)<<4 so LINEAR global_load_lds is
// bank-conflict-free for ds_read_b128 fragments (LDS row = wp = w+1).
// plane(b,h) = 65536 B, batch = 8,388,608 B, tensor = 32 MB.
//
// Weights: per-(cohalf,step) 8KB blocks in per-lane-fragment order
//   [cohalf][step][coq(2)][f(4)][lane(64)][16B] -> A-frags load DIRECTLY to
// VGPRs, distance-2 prefetch into 3 statically-indexed register buffers
// (full unroll -> no dynamic indexing, no rotation moves). LDS holds only B
// (33,280B -> 3 blocks/CU); barriers only at outer boundaries (14 vs 78).

__device__ __forceinline__ u16 f2bf(float f) {
  unsigned u = __float_as_uint(f);
  unsigned r = u + 0x7fffu + ((u >> 16) & 1u);
  return (u16)(r >> 16);
}

__device__ __forceinline__ void gll16(const char* g, char* l) {
  __builtin_amdgcn_global_load_lds((const __attribute__((address_space(1))) void*)g,
                                   (__attribute__((address_space(3))) void*)l, 16, 0, 0);
}

// ---------------- BN prep: s = g*rsqrt(v+eps), t = b - m*s ----------------
__global__ void bn_prep_kernel(const float* __restrict__ g, const float* __restrict__ b,
                               const float* __restrict__ m, const float* __restrict__ v,
                               float* __restrict__ st) {
  int c = threadIdx.x;
  float s = g[c] * rsqrtf(v[c] + 1e-5f);
  st[c] = s;
  st[256 + c] = b[c] - m[c] * s;
}

// fold c1 BN into merge: t_p += t_c1 ; ratio = s_c1/s_p stored in c1's s-slot
__global__ void bn_fix_kernel(float* __restrict__ st) {
  int c = threadIdx.x;
  st[2 * 512 + 256 + c] += st[3 * 512 + 256 + c];
  st[3 * 512 + c] = st[3 * 512 + c] / st[2 * 512 + c];
}

// ---------------- weight prep: [cohalf][step(72)][coq][f][lane][16B] ----------------
// idx(u16): e=idx&7, lane=(idx>>3)&63, f=(idx>>9)&3, coq=(idx>>11)&1, blk=idx>>12
// blk = cohalf*72 + step; step = outer*12 + dwi*4 + kc; outer = half*3 + d;
// s = d*3 + dwi; co = cohalf*128 + coq*64 + f*16 + (lane&15);
// ci = half*128 + kc*32 + (lane>>4)*8 + e.
__global__ void wprep3_kernel(const float* __restrict__ w, u16* __restrict__ dst) {
  int idx = blockIdx.x * 256 + threadIdx.x;        // 589,824 u16
  int e = idx & 7, lane = (idx >> 3) & 63, f = (idx >> 9) & 3, coq = (idx >> 11) & 1;
  int blk = idx >> 12;
  int cohalf = blk / 72, step = blk % 72;
  int outer = step / 12, rr = step % 12, dwi = rr >> 2, kc = rr & 3;
  int half = outer / 3, d = outer % 3;
  int s = d * 3 + dwi;
  int co = cohalf * 128 + coq * 64 + f * 16 + (lane & 15);
  int ci = half * 128 + kc * 32 + (lane >> 4) * 8 + e;
  dst[idx] = f2bf(w[(co * 256 + ci) * 9 + s]);
}

// c1: blk = cohalf*8 + step, step = half2*4 + kc.
__global__ void wprep1_kernel(const float* __restrict__ w, u16* __restrict__ dst,
                              const float* __restrict__ ratio) {
  int idx = blockIdx.x * 256 + threadIdx.x;        // 65,536 u16
  int e = idx & 7, lane = (idx >> 3) & 63, f = (idx >> 9) & 3, coq = (idx >> 11) & 1;
  int blk = idx >> 12;
  int cohalf = blk >> 3, step = blk & 7;
  int half2 = step >> 2, kc = step & 3;
  int co = cohalf * 128 + coq * 64 + f * 16 + (lane & 15);
  int ci = half2 * 128 + kc * 32 + (lane >> 4) * 8 + e;
  dst[idx] = f2bf(w[co * 256 + ci] * ratio[co]);
}

// ---------------- NCHW fp32 -> staging layout bf16 ----------------
__global__ __launch_bounds__(256) void nchw_to_nhwc_kernel(const float* __restrict__ x,
                                                           char* __restrict__ xb) {
  __shared__ __align__(16) u16 tl[128 * 130];
  int bh = blockIdx.x; int b = bh >> 7, h = bh & 127;
  int t = threadIdx.x;
  for (int half = 0; half < 2; ++half) {
    __syncthreads();
    for (int i = 0; i < 64; ++i) {
      int cil = i * 2 + (t >> 7);
      int ci = half * 128 + cil;
      int w = t & 127;
      tl[w * 130 + cil] = f2bf(x[(size_t)((b * 256 + ci) * 128 + h) * 128 + w]);
    }
    __syncthreads();
    char* plane = xb + (size_t)(b * 128 + h) * 65536 + half * 32768;
    for (int i = 0; i < 32; ++i) {
      int w = i * 4 + (t >> 6);
      int c2 = (t & 63) * 2;   // u16 index within half
      unsigned v = *(const unsigned*)&tl[w * 130 + c2];
      *(unsigned*)(plane + w * 256 + ((c2 * 2) ^ (((w + 1) & 7) << 4))) = v;
    }
  }
}

// ---- B staging (256-thread block) ----
__device__ __forceinline__ void stage_b(const char* plane, char* ldsB, int t) {
  if (plane) {
    char* dst = ldsB + 256 + t * 16;             // rows wp 1..128
    const char* g = plane + t * 16;
#pragma unroll
    for (int r = 0; r < 8; ++r) gll16(g + r * 4096, dst + r * 4096);
  } else {
    int4 z = {0, 0, 0, 0};
#pragma unroll
    for (int r = 0; r < 8; ++r) *(int4*)(ldsB + 256 + r * 4096 + t * 16) = z;
  }
}

__device__ __forceinline__ const char* a_ptr(const char* wA1, const char* wA2, int step, int off) {
  const char* src = (step < 72) ? (wA1 + (size_t)step * 8192)
                                : (wA2 + (size_t)(step - 72) * 8192);
  return src + off;
}

__device__ __forceinline__ void zero_acc(f32x4 (&acc)[4][4]) {
  f32x4 z = {0.f, 0.f, 0.f, 0.f};
#pragma unroll
  for (int i = 0; i < 4; ++i)
#pragma unroll
    for (int j = 0; j < 4; ++j) acc[i][j] = z;
}

// ---------------- conv pipeline: A in regs (dist-2, 3 bufs), B in LDS ----------------
// Per outer: [release barrier] stage_b [ready barrier] then 12 BARRIER-FREE steps:
//   { load aB[(j+2)%3] (4x dwordx4, L2) | ds_read 4 B-frags | 16 MFMA on aB[j%3] }.
__device__ __forceinline__ void conv_pipeline(const char* inB1, const char* inB2,
                                              const char* wA1, const char* wA2,
                                              int h, int nsteps, char* lds,
                                              f32x4 (&acc)[4][4]) {
  const int t = threadIdx.x;
  const int wv = t >> 6, lane = t & 63;
  const int lane15 = lane & 15, q = lane >> 4;
  const int coq = wv >> 1, wh = wv & 1;
  char* ldsB = lds;
  const int aoff = coq * 4096 + lane * 16;

  int wpb[4];
#pragma unroll
  for (int f = 0; f < 4; ++f) wpb[f] = wh * 64 + f * 16 + lane15;

  // zero pad rows 0 (w=-1) and 129 (w=128) ONCE; stage_b only writes rows 1..128.
  {
    int4 z = {0, 0, 0, 0};
    if (t < 16) *(int4*)(ldsB + t * 16) = z;
    else if (t < 32) *(int4*)(ldsB + 33024 + (t - 16) * 16) = z;
  }

  bf16x8 aB[3][4];
  {
    const char* p0 = a_ptr(wA1, wA2, 0, aoff);
    const char* p1 = a_ptr(wA1, wA2, 1, aoff);
#pragma unroll
    for (int f = 0; f < 4; ++f) aB[0][f] = *(const bf16x8*)(p0 + f * 1024);
#pragma unroll
    for (int f = 0; f < 4; ++f) aB[1][f] = *(const bf16x8*)(p1 + f * 1024);
  }

  for (int outer = 0; outer < 6; ++outer) {
    const int half = (outer >= 3) ? 1 : 0;
    const int d = outer - half * 3;
    const int hs = h + d - 1;
    const char* plane = (hs >= 0 && hs < 128)
                            ? inB1 + (size_t)hs * 65536 + (size_t)half * 32768
                            : nullptr;
    __syncthreads();                 // release ldsB (previous outer's readers done)
    stage_b(plane, ldsB, t);
    __syncthreads();                 // B ready
#pragma unroll
    for (int j = 0; j < 12; ++j) {
      const int dwi = j >> 2, kc = j & 3;
      const int cb = j % 3, pf = (j + 2) % 3;   // 12 % 3 == 0 -> phase continuous
      int sg = outer * 12 + j + 2;
      if (sg >= nsteps) sg = nsteps - 1;
      const char* p = a_ptr(wA1, wA2, sg, aoff);
#pragma unroll
      for (int f = 0; f < 4; ++f) aB[pf][f] = *(const bf16x8*)(p + f * 1024);
      bf16x8 bf[4];
#pragma unroll
      for (int f = 0; f < 4; ++f) {
        int wp = wpb[f] + dwi;
        bf[f] = *(const bf16x8*)(ldsB + wp * 256 + ((kc * 64 + q * 16) ^ ((wp & 7) << 4)));
      }
      __builtin_amdgcn_s_setprio(1);
#pragma unroll
      for (int fm = 0; fm < 4; ++fm)
#pragma unroll
        for (int fn = 0; fn < 4; ++fn)
          acc[fm][fn] = __builtin_amdgcn_mfma_f32_16x16x32_bf16(aB[cb][fm], bf[fn], acc[fm][fn], 0, 0, 0);
      __builtin_amdgcn_s_setprio(0);
    }
  }
  if (nsteps > 72) {   // fused 1x1 (c1): steps 72..79, B rows = input row h, dw=0
#pragma unroll
    for (int half2 = 0; half2 < 2; ++half2) {
      __syncthreads();
      stage_b(inB2 + (size_t)h * 65536 + (size_t)half2 * 32768, ldsB, t);
      __syncthreads();
#pragma unroll
      for (int j2 = 0; j2 < 4; ++j2) {
        const int jg = half2 * 4 + j2;            // global step = 72+jg; 72%3==0
        const int cb = jg % 3, pf = (jg + 2) % 3;
        int sg = 72 + jg + 2;
        if (sg >= nsteps) sg = nsteps - 1;
        const char* p = a_ptr(wA1, wA2, sg, aoff);
#pragma unroll
        for (int f = 0; f < 4; ++f) aB[pf][f] = *(const bf16x8*)(p + f * 1024);
        bf16x8 bf[4];
#pragma unroll
        for (int f = 0; f < 4; ++f) {
          int wp = wpb[f] + 1;
          bf[f] = *(const bf16x8*)(ldsB + wp * 256 + ((j2 * 64 + q * 16) ^ ((wp & 7) << 4)));
        }
        __builtin_amdgcn_s_setprio(1);
#pragma unroll
        for (int fm = 0; fm < 4; ++fm)
#pragma unroll
          for (int fn = 0; fn < 4; ++fn)
            acc[fm][fn] = __builtin_amdgcn_mfma_f32_16x16x32_bf16(aB[cb][fm], bf[fn], acc[fm][fn], 0, 0, 0);
        __builtin_amdgcn_s_setprio(0);
      }
    }
  }
}

// BN+ReLU, store to staging layout (8B = 4 co per lane); block covers co-half `cohalf`.
__device__ __forceinline__ void store_pad_relu(f32x4 (&acc)[4][4], const float* __restrict__ st,
                                               int cohalf, int b, int h, char* __restrict__ out) {
  const int t = threadIdx.x, lane = t & 63, wv = t >> 6;
  const int lane15 = lane & 15, q = lane >> 4, coq = wv >> 1, wh = wv & 1;
  char* plane = out + (size_t)(b * 128 + h) * 65536 + cohalf * 32768;
#pragma unroll
  for (int fm = 0; fm < 4; ++fm) {
    int co_l = coq * 64 + fm * 16 + q * 4;
    int co = cohalf * 128 + co_l;
    float ss[4], tt[4];
#pragma unroll
    for (int r = 0; r < 4; ++r) { ss[r] = st[co + r]; tt[r] = st[256 + co + r]; }
#pragma unroll
    for (int fn = 0; fn < 4; ++fn) {
      int w = wh * 64 + fn * 16 + lane15;
      short4 o;
      o.x = (short)f2bf(fmaxf(acc[fm][fn][0] * ss[0] + tt[0], 0.f));
      o.y = (short)f2bf(fmaxf(acc[fm][fn][1] * ss[1] + tt[1], 0.f));
      o.z = (short)f2bf(fmaxf(acc[fm][fn][2] * ss[2] + tt[2], 0.f));
      o.w = (short)f2bf(fmaxf(acc[fm][fn][3] * ss[3] + tt[3], 0.f));
      *(short4*)(plane + w * 256 + ((co_l * 2) ^ (((w + 1) & 7) << 4))) = o;
    }
  }
}

// ---------------- up conv: BN+ReLU then fused row-max over W ----------------
__global__ __launch_bounds__(256, 3) void conv_up_kernel(const char* __restrict__ xb,
                                                         const char* __restrict__ wp,
                                                         const float* __restrict__ st,
                                                         float* __restrict__ rmax) {
  __shared__ __align__(16) char lds[33280];
  int swz = (blockIdx.x & 7) * 64 + (blockIdx.x >> 3);
  int b = swz >> 7, h = swz & 127;
  int cohalf = blockIdx.y;
  const char* wA = wp + (size_t)cohalf * 589824;
  f32x4 acc[4][4];
  zero_acc(acc);
  conv_pipeline(xb + (size_t)b * 8388608, nullptr, wA, wA, h, 72, lds, acc);

  const int t = threadIdx.x, lane = t & 63, wv = t >> 6;
  const int lane15 = lane & 15, q = lane >> 4, coq = wv >> 1, wh = wv & 1;
  float* rlds = (float*)lds;
  __syncthreads();
#pragma unroll
  for (int fm = 0; fm < 4; ++fm) {
    int co_l = coq * 64 + fm * 16 + q * 4;
    int co = cohalf * 128 + co_l;
#pragma unroll
    for (int r = 0; r < 4; ++r) {
      float ss = st[co + r], tt = st[256 + co + r];
      float v = 0.f;   // ReLU floor
#pragma unroll
      for (int fn = 0; fn < 4; ++fn) v = fmaxf(v, acc[fm][fn][r] * ss + tt);
      v = fmaxf(v, __shfl_xor(v, 1));
      v = fmaxf(v, __shfl_xor(v, 2));
      v = fmaxf(v, __shfl_xor(v, 4));
      v = fmaxf(v, __shfl_xor(v, 8));
      if (lane15 == 0) rlds[wh * 128 + co_l + r] = v;
    }
  }
  __syncthreads();
  if (t < 128)
    rmax[(size_t)(b * 128 + h) * 256 + cohalf * 128 + t] = fmaxf(rlds[t], rlds[128 + t]);
}

// ---------------- down conv ----------------
__global__ __launch_bounds__(256, 3) void conv_down_kernel(const char* __restrict__ xb,
                                                           const char* __restrict__ wp,
                                                           const float* __restrict__ st,
                                                           char* __restrict__ out) {
  __shared__ __align__(16) char lds[33280];
  int swz = (blockIdx.x & 7) * 64 + (blockIdx.x >> 3);
  int b = swz >> 7, h = swz & 127;
  int cohalf = blockIdx.y;
  const char* wA = wp + (size_t)cohalf * 589824;
  f32x4 acc[4][4];
  zero_acc(acc);
  conv_pipeline(xb + (size_t)b * 8388608, nullptr, wA, wA, h, 72, lds, acc);
  store_pad_relu(acc, st, cohalf, b, h, out);
}

// ---------------- col max over H ----------------
__global__ __launch_bounds__(256) void colmax_kernel(const char* __restrict__ dp,
                                                     float* __restrict__ cmax) {
  int bw = blockIdx.x; int b = bw >> 7, w = bw & 127;
  int c = threadIdx.x;
  size_t base = (size_t)b * 8388608 + (size_t)(c >> 7) * 32768 + w * 256 +
                (((c & 127) * 2) ^ (((w + 1) & 7) << 4));
  float m = 0.f;
  for (int h = 0; h < 128; ++h) {
    u16 raw = *(const u16*)(dp + base + (size_t)h * 65536);
    m = fmaxf(m, __uint_as_float(((unsigned)raw) << 16));
  }
  cmax[(size_t)(b * 128 + w) * 256 + c] = m;
}

// ---------------- pooled = rmax[b,h,c] + cmax[b,w,c] (vectorized 16B stores) --------
// plane = 65,536 B = 4096 x 16B chunks: id = it*256 + t, it < 16.
// half = id>>11, w = (id&2047)>>4, slot = id&15; c0 = half*128 + slot*8;
// swizzled byte-in-row = (slot ^ ((w+1)&7)) << 4  (key XORs bits 4..6 only).
__global__ __launch_bounds__(256) void pooled_kernel(const float* __restrict__ rmax,
                                                     const float* __restrict__ cmax,
                                                     char* __restrict__ dp) {
  int bh = blockIdx.x; int b = bh >> 7, h = bh & 127;
  int t = threadIdx.x;
  char* plane = dp + (size_t)(b * 128 + h) * 65536;
  const float* rm = rmax + (size_t)(b * 128 + h) * 256;
#pragma unroll
  for (int it = 0; it < 16; ++it) {
    int id = it * 256 + t;                 // 0..4095 chunk of 16B
    int half = id >> 11, rem = id & 2047;
    int w = rem >> 4, slot = rem & 15;
    int c0 = half * 128 + slot * 8;
    const float* cm = cmax + (size_t)(b * 128 + w) * 256 + c0;
    const float* rr = rm + c0;
    u16 e[8];
#pragma unroll
    for (int k = 0; k < 8; ++k) e[k] = f2bf(rr[k] + cm[k]);
    int4 v;
    v.x = (int)(e[0] | ((unsigned)e[1] << 16));
    v.y = (int)(e[2] | ((unsigned)e[3] << 16));
    v.z = (int)(e[4] | ((unsigned)e[5] << 16));
    v.w = (int)(e[6] | ((unsigned)e[7] << 16));
    *(int4*)(plane + half * 32768 + w * 256 + ((slot ^ ((w + 1) & 7)) << 4)) = v;
  }
}

// ---------------- merge conv (pooled 3x3) + fused c1 (1x1 on xb) ----------------
__global__ __launch_bounds__(256, 3) void conv_merge_kernel(const char* __restrict__ dp,
                                                            const char* __restrict__ xb,
                                                            const char* __restrict__ wp_p,
                                                            const char* __restrict__ wp_c1,
                                                            const float* __restrict__ st,
                                                            char* __restrict__ out) {
  __shared__ __align__(16) char lds[33280];
  int swz = (blockIdx.x & 7) * 64 + (blockIdx.x >> 3);
  int b = swz >> 7, h = swz & 127;
  int cohalf = blockIdx.y;
  f32x4 acc[4][4];
  zero_acc(acc);
  conv_pipeline(dp + (size_t)b * 8388608, xb + (size_t)b * 8388608,
                wp_p + (size_t)cohalf * 589824, wp_c1 + (size_t)cohalf * 65536,
                h, 80, lds, acc);
  store_pad_relu(acc, st, cohalf, b, h, out);
}

// ---------------- final conv c2: BN+ReLU, NCHW fp32 out via LDS transpose ----------------
__global__ __launch_bounds__(256, 3) void conv_c2_kernel(const char* __restrict__ relu1,
                                                         const char* __restrict__ wp,
                                                         const float* __restrict__ st,
                                                         float* __restrict__ out) {
  __shared__ __align__(16) char lds[33280];
  int swz = (blockIdx.x & 7) * 64 + (blockIdx.x >> 3);
  int b = swz >> 7, h = swz & 127;
  int cohalf = blockIdx.y;
  const char* wA = wp + (size_t)cohalf * 589824;
  f32x4 acc[4][4];
  zero_acc(acc);
  conv_pipeline(relu1 + (size_t)b * 8388608, nullptr, wA, wA, h, 72, lds, acc);

  const int t = threadIdx.x, lane = t & 63, wv = t >> 6;
  const int lane15 = lane & 15, q = lane >> 4, coq = wv >> 1, wh = wv & 1;
  float* tl = (float*)lds;   // [16][132]
  for (int g = 0; g < 8; ++g) {
    __syncthreads();
    if (coq == (g >> 2)) {
      int fm = g & 3;
      int co_l = coq * 64 + fm * 16 + q * 4;
      int co = cohalf * 128 + co_l;
#pragma unroll
      for (int r = 0; r < 4; ++r) {
        float ss = st[co + r], tt = st[256 + co + r];
#pragma unroll
        for (int fn = 0; fn < 4; ++fn) {
          int w = wh * 64 + fn * 16 + lane15;
          tl[(q * 4 + r) * 132 + w] = fmaxf(acc[fm][fn][r] * ss + tt, 0.f);
        }
      }
    }
    __syncthreads();
    int row = t >> 4, ch = t & 15;
    int co = cohalf * 128 + g * 16 + row;
    float* dst = out + (size_t)((b * 256 + co) * 128 + h) * 128 + ch * 8;
    float4 p0 = *(float4*)&tl[row * 132 + ch * 8];
    float4 p1 = *(float4*)&tl[row * 132 + ch * 8 + 4];
    *(float4*)dst = p0;
    *(float4*)(dst + 4) = p1;
  }
}

extern "C" void kernel_launch(void* const* d_in, const int* in_sizes, int n_in,
                              void* d_out, int out_size, void* d_ws, size_t ws_size,
                              hipStream_t stream) {
  (void)in_sizes; (void)n_in; (void)out_size; (void)ws_size;
  const float* x    = (const float*)d_in[0];
  const float* w_up = (const float*)d_in[1];
  const float* w_dn = (const float*)d_in[6];
  const float* w_p  = (const float*)d_in[11];
  const float* w_c1 = (const float*)d_in[16];
  const float* w_c2 = (const float*)d_in[21];

  // ws layout (bytes) — total 106,571,776
  char* ws = (char*)d_ws;
  char* xb    = ws;                         // 33,554,432 (32MB staging layout)
  char* dp    = ws + 33554432ull;           // 33,554,432 (down, then pooled)
  char* relu1 = ws + 67108864ull;           // 33,554,432
  char* wp_up = ws + 100663296ull;          // 1,179,648
  char* wp_dn = ws + 101842944ull;          // 1,179,648
  char* wp_p  = ws + 103022592ull;          // 1,179,648
  char* wp_c2 = ws + 104202240ull;          // 1,179,648
  char* wp_c1 = ws + 105381888ull;          // 131,072
  float* st   = (float*)(ws + 105512960ull);// 10,240
  float* rmax = (float*)(ws + 105523200ull);// 524,288
  float* cmax = (float*)(ws + 106047488ull);// 524,288

  bn_prep_kernel<<<1, 256, 0, stream>>>((const float*)d_in[2], (const float*)d_in[3],
                                        (const float*)d_in[4], (const float*)d_in[5], st);
  bn_prep_kernel<<<1, 256, 0, stream>>>((const float*)d_in[7], (const float*)d_in[8],
                                        (const float*)d_in[9], (const float*)d_in[10], st + 512);
  bn_prep_kernel<<<1, 256, 0, stream>>>((const float*)d_in[12], (const float*)d_in[13],
                                        (const float*)d_in[14], (const float*)d_in[15], st + 1024);
  bn_prep_kernel<<<1, 256, 0, stream>>>((const float*)d_in[17], (const float*)d_in[18],
                                        (const float*)d_in[19], (const float*)d_in[20], st + 1536);
  bn_prep_kernel<<<1, 256, 0, stream>>>((const float*)d_in[22], (const float*)d_in[23],
                                        (const float*)d_in[24], (const float*)d_in[25], st + 2048);
  bn_fix_kernel<<<1, 256, 0, stream>>>(st);

  wprep3_kernel<<<2304, 256, 0, stream>>>(w_up, (u16*)wp_up);
  wprep3_kernel<<<2304, 256, 0, stream>>>(w_dn, (u16*)wp_dn);
  wprep3_kernel<<<2304, 256, 0, stream>>>(w_p, (u16*)wp_p);
  wprep3_kernel<<<2304, 256, 0, stream>>>(w_c2, (u16*)wp_c2);
  wprep1_kernel<<<256, 256, 0, stream>>>(w_c1, (u16*)wp_c1, st + 1536);

  nchw_to_nhwc_kernel<<<512, 256, 0, stream>>>(x, xb);

  conv_up_kernel<<<dim3(512, 2), 256, 0, stream>>>(xb, wp_up, st, rmax);
  conv_down_kernel<<<dim3(512, 2), 256, 0, stream>>>(xb, wp_dn, st + 512, dp);
  colmax_kernel<<<512, 256, 0, stream>>>(dp, cmax);
  pooled_kernel<<<512, 256, 0, stream>>>(rmax, cmax, dp);
  conv_merge_kernel<<<dim3(512, 2), 256, 0, stream>>>(dp, xb, wp_p, wp_c1, st + 1024, relu1);
  conv_c2_kernel<<<dim3(512, 2), 256, 0, stream>>>(relu1, wp_c2, st + 2048, (float*)d_out);
}

// Round 10
// 399.498 us; speedup vs baseline: 1.1144x; 1.1144x over previous
//
#include <hip/hip_runtime.h>

typedef unsigned short u16;
typedef __attribute__((ext_vector_type(8))) short bf16x8;
typedef __attribute__((ext_vector_type(4))) float f32x4;

// B=4, C=Cin=256, H=W=128.
// Activations: staging-ready global layout [b][h][half(ci>>7)][w][256B], each
// 256B half-row XOR-swizzled by key ((w+1)&7)<<4 so LINEAR global_load_lds is
// bank-conflict-free for ds_read_b128 fragments (LDS row = wp = w+1).
// plane(b,h) = 65536 B, batch = 8,388,608 B, tensor = 32 MB.
//
// Conv blocks: 256 threads (4 waves), tile [128co x 128w] at fixed (b,h),
// grid (512, 2 co-halves). LDS 49,664 B -> 3 blocks/CU. Weights staged via
// global_load_lds (r5 structure); per-step schedule upgraded to T4 counted
// vmcnt: stageA(i+1) -> vmcnt(2) -> s_barrier -> ds_read -> MFMA -> s_barrier,
// so the A-prefetch stays in flight ACROSS the barrier (no per-step drain).

__device__ __forceinline__ u16 f2bf(float f) {
  unsigned u = __float_as_uint(f);
  unsigned r = u + 0x7fffu + ((u >> 16) & 1u);
  return (u16)(r >> 16);
}

__device__ __forceinline__ void gll16(const char* g, char* l) {
  __builtin_amdgcn_global_load_lds((const __attribute__((address_space(1))) void*)g,
                                   (__attribute__((address_space(3))) void*)l, 16, 0, 0);
}

// ---------------- BN prep: s = g*rsqrt(v+eps), t = b - m*s ----------------
__global__ void bn_prep_kernel(const float* __restrict__ g, const float* __restrict__ b,
                               const float* __restrict__ m, const float* __restrict__ v,
                               float* __restrict__ st) {
  int c = threadIdx.x;
  float s = g[c] * rsqrtf(v[c] + 1e-5f);
  st[c] = s;
  st[256 + c] = b[c] - m[c] * s;
}

// fold c1 BN into merge: t_p += t_c1 ; ratio = s_c1/s_p stored in c1's s-slot
__global__ void bn_fix_kernel(float* __restrict__ st) {
  int c = threadIdx.x;
  st[2 * 512 + 256 + c] += st[3 * 512 + 256 + c];
  st[3 * 512 + c] = st[3 * 512 + c] / st[2 * 512 + c];
}

// ---------------- weight prep: per-(cohalf,step) 8KB blocks in exact LDS image ---------
// Block layout: [cohalf(2)][step(72)][128 co_l rows x 64B]. Within a row, the 4
// 16B slots are XOR-swizzled by key (co_l>>1)&3. step = outer*12 + dwi*4 + kc,
// outer = half*3 + d  (half = ci>>7, d = dh+1), s = d*3 + dwi,
// ci = half*128 + kc*32 + q*8 + e with q = slot ^ key.
__global__ void wprep3_kernel(const float* __restrict__ w, u16* __restrict__ dst) {
  int idx = blockIdx.x * 256 + threadIdx.x;        // 589,824 u16
  int blk = idx >> 12, iu = idx & 4095;
  int co_l = iu >> 5, w32 = iu & 31, slot = w32 >> 3, e = w32 & 7;
  int q = slot ^ ((co_l >> 1) & 3);
  int cohalf = blk / 72, step = blk % 72;
  int outer = step / 12, rr = step % 12, dwi = rr >> 2, kc = rr & 3;
  int half = outer / 3, d = outer % 3;
  int s = d * 3 + dwi;
  int ci = half * 128 + kc * 32 + q * 8 + e;
  int co = cohalf * 128 + co_l;
  dst[idx] = f2bf(w[(co * 256 + ci) * 9 + s]);
}

// c1: [cohalf(2)][step(8 = half2*4+kc)][128 x 64B], same row swizzle.
__global__ void wprep1_kernel(const float* __restrict__ w, u16* __restrict__ dst,
                              const float* __restrict__ ratio) {
  int idx = blockIdx.x * 256 + threadIdx.x;        // 65,536 u16
  int blk = idx >> 12, iu = idx & 4095;
  int co_l = iu >> 5, w32 = iu & 31, slot = w32 >> 3, e = w32 & 7;
  int q = slot ^ ((co_l >> 1) & 3);
  int cohalf = blk >> 3, j = blk & 7;
  int half2 = j >> 2, kc = j & 3;
  int ci = half2 * 128 + kc * 32 + q * 8 + e;
  int co = cohalf * 128 + co_l;
  dst[idx] = f2bf(w[co * 256 + ci] * ratio[co]);
}

// ---------------- NCHW fp32 -> staging layout bf16 ----------------
__global__ __launch_bounds__(256) void nchw_to_nhwc_kernel(const float* __restrict__ x,
                                                           char* __restrict__ xb) {
  __shared__ __align__(16) u16 tl[128 * 130];
  int bh = blockIdx.x; int b = bh >> 7, h = bh & 127;
  int t = threadIdx.x;
  for (int half = 0; half < 2; ++half) {
    __syncthreads();
    for (int i = 0; i < 64; ++i) {
      int cil = i * 2 + (t >> 7);
      int ci = half * 128 + cil;
      int w = t & 127;
      tl[w * 130 + cil] = f2bf(x[(size_t)((b * 256 + ci) * 128 + h) * 128 + w]);
    }
    __syncthreads();
    char* plane = xb + (size_t)(b * 128 + h) * 65536 + half * 32768;
    for (int i = 0; i < 32; ++i) {
      int w = i * 4 + (t >> 6);
      int c2 = (t & 63) * 2;   // u16 index within half
      unsigned v = *(const unsigned*)&tl[w * 130 + c2];
      *(unsigned*)(plane + w * 256 + ((c2 * 2) ^ (((w + 1) & 7) << 4))) = v;
    }
  }
}

// ---- staging helpers (256-thread block): plain free functions ----
__device__ __forceinline__ void stage_a(const char* wA1, const char* wA2, int step,
                                        char* ldsA0, int buf, int t) {
  const char* src = (step < 72) ? (wA1 + (size_t)step * 8192)
                                : (wA2 + (size_t)(step - 72) * 8192);
  char* dst = ldsA0 + buf * 8192 + t * 16;
  const char* g = src + t * 16;
  gll16(g, dst);
  gll16(g + 4096, dst + 4096);
}

__device__ __forceinline__ void stage_b(const char* plane, char* ldsB, int t) {
  if (plane) {
    char* dst = ldsB + 256 + t * 16;             // rows wp 1..128
    const char* g = plane + t * 16;
#pragma unroll
    for (int r = 0; r < 8; ++r) gll16(g + r * 4096, dst + r * 4096);
  } else {
    int4 z = {0, 0, 0, 0};
#pragma unroll
    for (int r = 0; r < 8; ++r) *(int4*)(ldsB + 256 + r * 4096 + t * 16) = z;
  }
}

__device__ __forceinline__ void zero_acc(f32x4 (&acc)[4][4]) {
  f32x4 z = {0.f, 0.f, 0.f, 0.f};
#pragma unroll
  for (int i = 0; i < 4; ++i)
#pragma unroll
    for (int j = 0; j < 4; ++j) acc[i][j] = z;
}

// ---------------- shared 4-wave conv pipeline (T4 counted-vmcnt) ----------------
// LDS: B rows wp 0..129 (33,280B) + A double-buffer 2x8,192B = 49,664B.
// Per step: stageA(i+1) -> vmcnt(2) lgkmcnt(0) -> s_barrier (arrival) ->
//   sched_barrier -> ds_read 8 frags -> setprio(1) 16 MFMA setprio(0) ->
//   s_barrier (release). The just-issued prefetch (2 loads) crosses both
//   barriers in flight; vmcnt FIFO forces A[i] + any B DMA complete.
#define CONV_STEP(WP_ADD, KC)                                                              \
  {                                                                                        \
    if (i + 1 < nsteps) {                                                                  \
      stage_a(wA1, wA2, i + 1, ldsA0, cur ^ 1, t);                                         \
      asm volatile("s_waitcnt vmcnt(2) lgkmcnt(0)" ::: "memory");                          \
    } else {                                                                               \
      asm volatile("s_waitcnt vmcnt(0) lgkmcnt(0)" ::: "memory");                          \
    }                                                                                      \
    __builtin_amdgcn_s_barrier();                                                          \
    __builtin_amdgcn_sched_barrier(0);                                                     \
    bf16x8 af[4], bf[4];                                                                   \
    const char* lA = ldsA0 + cur * 8192;                                                   \
    _Pragma("unroll")                                                                      \
    for (int f = 0; f < 4; ++f) af[f] = *(const bf16x8*)(lA + aOff[f]);                    \
    _Pragma("unroll")                                                                      \
    for (int f = 0; f < 4; ++f) {                                                          \
      int wp = wpb[f] + (WP_ADD);                                                          \
      bf[f] = *(const bf16x8*)(ldsB + wp * 256 + (((KC)*64 + q * 16) ^ ((wp & 7) << 4)));  \
    }                                                                                      \
    __builtin_amdgcn_s_setprio(1);                                                         \
    _Pragma("unroll")                                                                      \
    for (int fm = 0; fm < 4; ++fm)                                                         \
      _Pragma("unroll")                                                                    \
      for (int fn = 0; fn < 4; ++fn)                                                       \
        acc[fm][fn] =                                                                      \
            __builtin_amdgcn_mfma_f32_16x16x32_bf16(af[fm], bf[fn], acc[fm][fn], 0, 0, 0); \
    __builtin_amdgcn_s_setprio(0);                                                         \
    __builtin_amdgcn_s_barrier();                                                          \
    cur ^= 1;                                                                              \
    ++i;                                                                                   \
  }

__device__ __forceinline__ void conv_pipeline(const char* inB1, const char* inB2,
                                              const char* wA1, const char* wA2,
                                              int h, int nsteps, char* lds,
                                              f32x4 (&acc)[4][4]) {
  const int t = threadIdx.x;
  const int wv = t >> 6, lane = t & 63;
  const int lane15 = lane & 15, q = lane >> 4;
  const int coq = wv >> 1, wh = wv & 1;
  char* ldsB = lds;
  char* ldsA0 = lds + 33280;

  int aOff[4];
#pragma unroll
  for (int f = 0; f < 4; ++f) {
    int ra = coq * 64 + f * 16 + lane15;          // co_l in [0,128)
    aOff[f] = ra * 64 + ((q ^ ((ra >> 1) & 3)) << 4);
  }
  int wpb[4];
#pragma unroll
  for (int f = 0; f < 4; ++f) wpb[f] = wh * 64 + f * 16 + lane15;

  // zero pad rows 0 (w=-1) and 129 (w=128) ONCE; stage_b only writes rows 1..128.
  {
    int4 z = {0, 0, 0, 0};
    if (t < 16) *(int4*)(ldsB + t * 16) = z;
    else if (t < 32) *(int4*)(ldsB + 33024 + (t - 16) * 16) = z;
  }

  int cur = 0, i = 0;
  for (int outer = 0; outer < 6; ++outer) {
    const int half = (outer >= 3) ? 1 : 0;
    const int d = outer - half * 3;
    const int hs = h + d - 1;
    const char* plane = (hs >= 0 && hs < 128)
                            ? inB1 + (size_t)hs * 65536 + (size_t)half * 32768
                            : nullptr;
    // previous step's release barrier guarantees all reads of ldsB are done
    stage_b(plane, ldsB, t);
    if (outer == 0) stage_a(wA1, wA2, 0, ldsA0, 0, t);
#pragma unroll
    for (int dwi = 0; dwi < 3; ++dwi)
#pragma unroll
      for (int kc = 0; kc < 4; ++kc) CONV_STEP(dwi, kc)
  }
  if (nsteps > 72) {   // fused 1x1 (c1) segment: row h, dw=0 (wp = w+1)
    for (int half2 = 0; half2 < 2; ++half2) {
      stage_b(inB2 + (size_t)h * 65536 + (size_t)half2 * 32768, ldsB, t);
#pragma unroll
      for (int kc = 0; kc < 4; ++kc) CONV_STEP(1, kc)
    }
  }
}

// BN+ReLU, store to staging layout (8B = 4 co per lane); block covers co-half `cohalf`.
__device__ __forceinline__ void store_pad_relu(f32x4 (&acc)[4][4], const float* __restrict__ st,
                                               int cohalf, int b, int h, char* __restrict__ out) {
  const int t = threadIdx.x, lane = t & 63, wv = t >> 6;
  const int lane15 = lane & 15, q = lane >> 4, coq = wv >> 1, wh = wv & 1;
  char* plane = out + (size_t)(b * 128 + h) * 65536 + cohalf * 32768;
#pragma unroll
  for (int fm = 0; fm < 4; ++fm) {
    int co_l = coq * 64 + fm * 16 + q * 4;
    int co = cohalf * 128 + co_l;
    float ss[4], tt[4];
#pragma unroll
    for (int r = 0; r < 4; ++r) { ss[r] = st[co + r]; tt[r] = st[256 + co + r]; }
#pragma unroll
    for (int fn = 0; fn < 4; ++fn) {
      int w = wh * 64 + fn * 16 + lane15;
      short4 o;
      o.x = (short)f2bf(fmaxf(acc[fm][fn][0] * ss[0] + tt[0], 0.f));
      o.y = (short)f2bf(fmaxf(acc[fm][fn][1] * ss[1] + tt[1], 0.f));
      o.z = (short)f2bf(fmaxf(acc[fm][fn][2] * ss[2] + tt[2], 0.f));
      o.w = (short)f2bf(fmaxf(acc[fm][fn][3] * ss[3] + tt[3], 0.f));
      *(short4*)(plane + w * 256 + ((co_l * 2) ^ (((w + 1) & 7) << 4))) = o;
    }
  }
}

// ---------------- up conv: BN+ReLU then fused row-max over W ----------------
__global__ __launch_bounds__(256, 3) void conv_up_kernel(const char* __restrict__ xb,
                                                         const char* __restrict__ wp,
                                                         const float* __restrict__ st,
                                                         float* __restrict__ rmax) {
  __shared__ __align__(16) char lds[49664];
  int swz = (blockIdx.x & 7) * 64 + (blockIdx.x >> 3);
  int b = swz >> 7, h = swz & 127;
  int cohalf = blockIdx.y;
  const char* wA = wp + (size_t)cohalf * 589824;
  f32x4 acc[4][4];
  zero_acc(acc);
  conv_pipeline(xb + (size_t)b * 8388608, nullptr, wA, wA, h, 72, lds, acc);

  const int t = threadIdx.x, lane = t & 63, wv = t >> 6;
  const int lane15 = lane & 15, q = lane >> 4, coq = wv >> 1, wh = wv & 1;
  float* rlds = (float*)lds;
  __syncthreads();
#pragma unroll
  for (int fm = 0; fm < 4; ++fm) {
    int co_l = coq * 64 + fm * 16 + q * 4;
    int co = cohalf * 128 + co_l;
#pragma unroll
    for (int r = 0; r < 4; ++r) {
      float ss = st[co + r], tt = st[256 + co + r];
      float v = 0.f;   // ReLU floor
#pragma unroll
      for (int fn = 0; fn < 4; ++fn) v = fmaxf(v, acc[fm][fn][r] * ss + tt);
      v = fmaxf(v, __shfl_xor(v, 1));
      v = fmaxf(v, __shfl_xor(v, 2));
      v = fmaxf(v, __shfl_xor(v, 4));
      v = fmaxf(v, __shfl_xor(v, 8));
      if (lane15 == 0) rlds[wh * 128 + co_l + r] = v;
    }
  }
  __syncthreads();
  if (t < 128)
    rmax[(size_t)(b * 128 + h) * 256 + cohalf * 128 + t] = fmaxf(rlds[t], rlds[128 + t]);
}

// ---------------- down conv ----------------
__global__ __launch_bounds__(256, 3) void conv_down_kernel(const char* __restrict__ xb,
                                                           const char* __restrict__ wp,
                                                           const float* __restrict__ st,
                                                           char* __restrict__ out) {
  __shared__ __align__(16) char lds[49664];
  int swz = (blockIdx.x & 7) * 64 + (blockIdx.x >> 3);
  int b = swz >> 7, h = swz & 127;
  int cohalf = blockIdx.y;
  const char* wA = wp + (size_t)cohalf * 589824;
  f32x4 acc[4][4];
  zero_acc(acc);
  conv_pipeline(xb + (size_t)b * 8388608, nullptr, wA, wA, h, 72, lds, acc);
  store_pad_relu(acc, st, cohalf, b, h, out);
}

// ---------------- col max over H ----------------
__global__ __launch_bounds__(256) void colmax_kernel(const char* __restrict__ dp,
                                                     float* __restrict__ cmax) {
  int bw = blockIdx.x; int b = bw >> 7, w = bw & 127;
  int c = threadIdx.x;
  size_t base = (size_t)b * 8388608 + (size_t)(c >> 7) * 32768 + w * 256 +
                (((c & 127) * 2) ^ (((w + 1) & 7) << 4));
  float m = 0.f;
  for (int h = 0; h < 128; ++h) {
    u16 raw = *(const u16*)(dp + base + (size_t)h * 65536);
    m = fmaxf(m, __uint_as_float(((unsigned)raw) << 16));
  }
  cmax[(size_t)(b * 128 + w) * 256 + c] = m;
}

// ---------------- pooled = rmax[b,h,c] + cmax[b,w,c] (vectorized 16B stores) --------
// plane = 65,536 B = 4096 x 16B chunks: id = it*256 + t, it < 16.
// half = id>>11, w = (id&2047)>>4, slot = id&15; c0 = half*128 + slot*8;
// swizzled byte-in-row = (slot ^ ((w+1)&7)) << 4  (key XORs bits 4..6 only).
__global__ __launch_bounds__(256) void pooled_kernel(const float* __restrict__ rmax,
                                                     const float* __restrict__ cmax,
                                                     char* __restrict__ dp) {
  int bh = blockIdx.x; int b = bh >> 7, h = bh & 127;
  int t = threadIdx.x;
  char* plane = dp + (size_t)(b * 128 + h) * 65536;
  const float* rm = rmax + (size_t)(b * 128 + h) * 256;
#pragma unroll
  for (int it = 0; it < 16; ++it) {
    int id = it * 256 + t;                 // 0..4095 chunk of 16B
    int half = id >> 11, rem = id & 2047;
    int w = rem >> 4, slot = rem & 15;
    int c0 = half * 128 + slot * 8;
    const float* cm = cmax + (size_t)(b * 128 + w) * 256 + c0;
    const float* rr = rm + c0;
    u16 e[8];
#pragma unroll
    for (int k = 0; k < 8; ++k) e[k] = f2bf(rr[k] + cm[k]);
    int4 v;
    v.x = (int)(e[0] | ((unsigned)e[1] << 16));
    v.y = (int)(e[2] | ((unsigned)e[3] << 16));
    v.z = (int)(e[4] | ((unsigned)e[5] << 16));
    v.w = (int)(e[6] | ((unsigned)e[7] << 16));
    *(int4*)(plane + half * 32768 + w * 256 + ((slot ^ ((w + 1) & 7)) << 4)) = v;
  }
}

// ---------------- merge conv (pooled 3x3) + fused c1 (1x1 on xb) ----------------
__global__ __launch_bounds__(256, 3) void conv_merge_kernel(const char* __restrict__ dp,
                                                            const char* __restrict__ xb,
                                                            const char* __restrict__ wp_p,
                                                            const char* __restrict__ wp_c1,
                                                            const float* __restrict__ st,
                                                            char* __restrict__ out) {
  __shared__ __align__(16) char lds[49664];
  int swz = (blockIdx.x & 7) * 64 + (blockIdx.x >> 3);
  int b = swz >> 7, h = swz & 127;
  int cohalf = blockIdx.y;
  f32x4 acc[4][4];
  zero_acc(acc);
  conv_pipeline(dp + (size_t)b * 8388608, xb + (size_t)b * 8388608,
                wp_p + (size_t)cohalf * 589824, wp_c1 + (size_t)cohalf * 65536,
                h, 80, lds, acc);
  store_pad_relu(acc, st, cohalf, b, h, out);
}

// ---------------- final conv c2: BN+ReLU, NCHW fp32 out via LDS transpose ----------------
__global__ __launch_bounds__(256, 3) void conv_c2_kernel(const char* __restrict__ relu1,
                                                         const char* __restrict__ wp,
                                                         const float* __restrict__ st,
                                                         float* __restrict__ out) {
  __shared__ __align__(16) char lds[49664];
  int swz = (blockIdx.x & 7) * 64 + (blockIdx.x >> 3);
  int b = swz >> 7, h = swz & 127;
  int cohalf = blockIdx.y;
  const char* wA = wp + (size_t)cohalf * 589824;
  f32x4 acc[4][4];
  zero_acc(acc);
  conv_pipeline(relu1 + (size_t)b * 8388608, nullptr, wA, wA, h, 72, lds, acc);

  const int t = threadIdx.x, lane = t & 63, wv = t >> 6;
  const int lane15 = lane & 15, q = lane >> 4, coq = wv >> 1, wh = wv & 1;
  float* tl = (float*)lds;   // [16][132]
  for (int g = 0; g < 8; ++g) {
    __syncthreads();
    if (coq == (g >> 2)) {
      int fm = g & 3;
      int co_l = coq * 64 + fm * 16 + q * 4;
      int co = cohalf * 128 + co_l;
#pragma unroll
      for (int r = 0; r < 4; ++r) {
        float ss = st[co + r], tt = st[256 + co + r];
#pragma unroll
        for (int fn = 0; fn < 4; ++fn) {
          int w = wh * 64 + fn * 16 + lane15;
          tl[(q * 4 + r) * 132 + w] = fmaxf(acc[fm][fn][r] * ss + tt, 0.f);
        }
      }
    }
    __syncthreads();
    int row = t >> 4, ch = t & 15;
    int co = cohalf * 128 + g * 16 + row;
    float* dst = out + (size_t)((b * 256 + co) * 128 + h) * 128 + ch * 8;
    float4 p0 = *(float4*)&tl[row * 132 + ch * 8];
    float4 p1 = *(float4*)&tl[row * 132 + ch * 8 + 4];
    *(float4*)dst = p0;
    *(float4*)(dst + 4) = p1;
  }
}

extern "C" void kernel_launch(void* const* d_in, const int* in_sizes, int n_in,
                              void* d_out, int out_size, void* d_ws, size_t ws_size,
                              hipStream_t stream) {
  (void)in_sizes; (void)n_in; (void)out_size; (void)ws_size;
  const float* x    = (const float*)d_in[0];
  const float* w_up = (const float*)d_in[1];
  const float* w_dn = (const float*)d_in[6];
  const float* w_p  = (const float*)d_in[11];
  const float* w_c1 = (const float*)d_in[16];
  const float* w_c2 = (const float*)d_in[21];

  // ws layout (bytes) — total 106,571,776
  char* ws = (char*)d_ws;
  char* xb    = ws;                         // 33,554,432 (32MB staging layout)
  char* dp    = ws + 33554432ull;           // 33,554,432 (down, then pooled)
  char* relu1 = ws + 67108864ull;           // 33,554,432
  char* wp_up = ws + 100663296ull;          // 1,179,648
  char* wp_dn = ws + 101842944ull;          // 1,179,648
  char* wp_p  = ws + 103022592ull;          // 1,179,648
  char* wp_c2 = ws + 104202240ull;          // 1,179,648
  char* wp_c1 = ws + 105381888ull;          // 131,072
  float* st   = (float*)(ws + 105512960ull);// 10,240
  float* rmax = (float*)(ws + 105523200ull);// 524,288
  float* cmax = (float*)(ws + 106047488ull);// 524,288

  bn_prep_kernel<<<1, 256, 0, stream>>>((const float*)d_in[2], (const float*)d_in[3],
                                        (const float*)d_in[4], (const float*)d_in[5], st);
  bn_prep_kernel<<<1, 256, 0, stream>>>((const float*)d_in[7], (const float*)d_in[8],
                                        (const float*)d_in[9], (const float*)d_in[10], st + 512);
  bn_prep_kernel<<<1, 256, 0, stream>>>((const float*)d_in[12], (const float*)d_in[13],
                                        (const float*)d_in[14], (const float*)d_in[15], st + 1024);
  bn_prep_kernel<<<1, 256, 0, stream>>>((const float*)d_in[17], (const float*)d_in[18],
                                        (const float*)d_in[19], (const float*)d_in[20], st + 1536);
  bn_prep_kernel<<<1, 256, 0, stream>>>((const float*)d_in[22], (const float*)d_in[23],
                                        (const float*)d_in[24], (const float*)d_in[25], st + 2048);
  bn_fix_kernel<<<1, 256, 0, stream>>>(st);

  wprep3_kernel<<<2304, 256, 0, stream>>>(w_up, (u16*)wp_up);
  wprep3_kernel<<<2304, 256, 0, stream>>>(w_dn, (u16*)wp_dn);
  wprep3_kernel<<<2304, 256, 0, stream>>>(w_p, (u16*)wp_p);
  wprep3_kernel<<<2304, 256, 0, stream>>>(w_c2, (u16*)wp_c2);
  wprep1_kernel<<<256, 256, 0, stream>>>(w_c1, (u16*)wp_c1, st + 1536);

  nchw_to_nhwc_kernel<<<512, 256, 0, stream>>>(x, xb);

  conv_up_kernel<<<dim3(512, 2), 256, 0, stream>>>(xb, wp_up, st, rmax);
  conv_down_kernel<<<dim3(512, 2), 256, 0, stream>>>(xb, wp_dn, st + 512, dp);
  colmax_kernel<<<512, 256, 0, stream>>>(dp, cmax);
  pooled_kernel<<<512, 256, 0, stream>>>(rmax, cmax, dp);
  conv_merge_kernel<<<dim3(512, 2), 256, 0, stream>>>(dp, xb, wp_p, wp_c1, st + 1024, relu1);
  conv_c2_kernel<<<dim3(512, 2), 256, 0, stream>>>(relu1, wp_c2, st + 2048, (float*)d_out);
}

// Round 11
// 397.658 us; speedup vs baseline: 1.1196x; 1.0046x over previous
//
#include <hip/hip_runtime.h>

typedef unsigned short u16;
typedef __attribute__((ext_vector_type(8))) short bf16x8;
typedef __attribute__((ext_vector_type(4))) float f32x4;

// B=4, C=Cin=256, H=W=128.
// Activations: staging-ready global layout [b][h][half(ci>>7)][w][256B], each
// 256B half-row XOR-swizzled by key ((w+1)&7)<<4 so LINEAR global_load_lds is
// bank-conflict-free for ds_read_b128 fragments (LDS row = wp = w+1).
// plane(b,h) = 65536 B, batch = 8,388,608 B, tensor = 32 MB.
//
// Conv blocks: 256 threads (4 waves), tile [128co x 128w] at fixed (b,h).
// A double-buffer is PER-WAVE PRIVATE (4KB = the wave's 64 co rows): each wave
// DMAs its own half (coq pair issues duplicate DMAs; L2 absorbs), self-paced
// with per-wave vmcnt(4). Barriers exist ONLY around B staging (16/block vs
// 146) -> waves desync inside an outer, overlapping ds_read/MFMA/DMA phases.
// LDS = B 33,280 + 4x8,192 A rings = 66,048 -> 2 blocks/CU.

__device__ __forceinline__ u16 f2bf(float f) {
  unsigned u = __float_as_uint(f);
  unsigned r = u + 0x7fffu + ((u >> 16) & 1u);
  return (u16)(r >> 16);
}

__device__ __forceinline__ void gll16(const char* g, char* l) {
  __builtin_amdgcn_global_load_lds((const __attribute__((address_space(1))) void*)g,
                                   (__attribute__((address_space(3))) void*)l, 16, 0, 0);
}

// ---------------- BN prep: s = g*rsqrt(v+eps), t = b - m*s ----------------
__global__ void bn_prep_kernel(const float* __restrict__ g, const float* __restrict__ b,
                               const float* __restrict__ m, const float* __restrict__ v,
                               float* __restrict__ st) {
  int c = threadIdx.x;
  float s = g[c] * rsqrtf(v[c] + 1e-5f);
  st[c] = s;
  st[256 + c] = b[c] - m[c] * s;
}

// fold c1 BN into merge: t_p += t_c1 ; ratio = s_c1/s_p stored in c1's s-slot
__global__ void bn_fix_kernel(float* __restrict__ st) {
  int c = threadIdx.x;
  st[2 * 512 + 256 + c] += st[3 * 512 + 256 + c];
  st[3 * 512 + c] = st[3 * 512 + c] / st[2 * 512 + c];
}

// ---------------- weight prep: per-(cohalf,step) 8KB blocks in exact LDS image ---------
// Block layout: [cohalf(2)][step(72)][128 co_l rows x 64B]. Within a row, the 4
// 16B slots are XOR-swizzled by key (co_l>>1)&3. step = outer*12 + dwi*4 + kc,
// outer = half*3 + d  (half = ci>>7, d = dh+1), s = d*3 + dwi,
// ci = half*128 + kc*32 + q*8 + e with q = slot ^ key.
__global__ void wprep3_kernel(const float* __restrict__ w, u16* __restrict__ dst) {
  int idx = blockIdx.x * 256 + threadIdx.x;        // 589,824 u16
  int blk = idx >> 12, iu = idx & 4095;
  int co_l = iu >> 5, w32 = iu & 31, slot = w32 >> 3, e = w32 & 7;
  int q = slot ^ ((co_l >> 1) & 3);
  int cohalf = blk / 72, step = blk % 72;
  int outer = step / 12, rr = step % 12, dwi = rr >> 2, kc = rr & 3;
  int half = outer / 3, d = outer % 3;
  int s = d * 3 + dwi;
  int ci = half * 128 + kc * 32 + q * 8 + e;
  int co = cohalf * 128 + co_l;
  dst[idx] = f2bf(w[(co * 256 + ci) * 9 + s]);
}

// c1: [cohalf(2)][step(8 = half2*4+kc)][128 x 64B], same row swizzle.
__global__ void wprep1_kernel(const float* __restrict__ w, u16* __restrict__ dst,
                              const float* __restrict__ ratio) {
  int idx = blockIdx.x * 256 + threadIdx.x;        // 65,536 u16
  int blk = idx >> 12, iu = idx & 4095;
  int co_l = iu >> 5, w32 = iu & 31, slot = w32 >> 3, e = w32 & 7;
  int q = slot ^ ((co_l >> 1) & 3);
  int cohalf = blk >> 3, j = blk & 7;
  int half2 = j >> 2, kc = j & 3;
  int ci = half2 * 128 + kc * 32 + q * 8 + e;
  int co = cohalf * 128 + co_l;
  dst[idx] = f2bf(w[co * 256 + ci] * ratio[co]);
}

// ---------------- NCHW fp32 -> staging layout bf16 ----------------
__global__ __launch_bounds__(256) void nchw_to_nhwc_kernel(const float* __restrict__ x,
                                                           char* __restrict__ xb) {
  __shared__ __align__(16) u16 tl[128 * 130];
  int bh = blockIdx.x; int b = bh >> 7, h = bh & 127;
  int t = threadIdx.x;
  for (int half = 0; half < 2; ++half) {
    __syncthreads();
    for (int i = 0; i < 64; ++i) {
      int cil = i * 2 + (t >> 7);
      int ci = half * 128 + cil;
      int w = t & 127;
      tl[w * 130 + cil] = f2bf(x[(size_t)((b * 256 + ci) * 128 + h) * 128 + w]);
    }
    __syncthreads();
    char* plane = xb + (size_t)(b * 128 + h) * 65536 + half * 32768;
    for (int i = 0; i < 32; ++i) {
      int w = i * 4 + (t >> 6);
      int c2 = (t & 63) * 2;   // u16 index within half
      unsigned v = *(const unsigned*)&tl[w * 130 + c2];
      *(unsigned*)(plane + w * 256 + ((c2 * 2) ^ (((w + 1) & 7) << 4))) = v;
    }
  }
}

// ---- staging helpers ----
// Per-wave A stage: the wave's own coq-half (4KB, rows coq*64..coq*64+63).
__device__ __forceinline__ void stage_aw(const char* wA1, const char* wA2, int step,
                                         char* ldsAw, int buf, int coq, int lane) {
  const char* src = (step < 72) ? (wA1 + (size_t)step * 8192)
                                : (wA2 + (size_t)(step - 72) * 8192);
  const char* g = src + coq * 4096 + lane * 16;
  char* dst = ldsAw + buf * 4096 + lane * 16;
#pragma unroll
  for (int k = 0; k < 4; ++k) gll16(g + k * 1024, dst + k * 1024);
}

__device__ __forceinline__ void stage_b(const char* plane, char* ldsB, int t) {
  if (plane) {
    char* dst = ldsB + 256 + t * 16;             // rows wp 1..128
    const char* g = plane + t * 16;
#pragma unroll
    for (int r = 0; r < 8; ++r) gll16(g + r * 4096, dst + r * 4096);
  } else {
    int4 z = {0, 0, 0, 0};
#pragma unroll
    for (int r = 0; r < 8; ++r) *(int4*)(ldsB + 256 + r * 4096 + t * 16) = z;
  }
}

__device__ __forceinline__ void zero_acc(f32x4 (&acc)[4][4]) {
  f32x4 z = {0.f, 0.f, 0.f, 0.f};
#pragma unroll
  for (int i = 0; i < 4; ++i)
#pragma unroll
    for (int j = 0; j < 4; ++j) acc[i][j] = z;
}

// ---------------- conv pipeline: barrier-free inner steps ----------------
// Per outer: lgkmcnt(0)+s_barrier (release B) -> stage_b -> vmcnt(0)+lgkmcnt(0)
// +s_barrier (B ready; also forces own A buf) -> 12 steps with NO barriers:
//   { stage own A(i+1) -> vmcnt(4) (forces A(i), per-wave) -> ds_read -> MFMA }.
#define CONV_STEP(WP_ADD, KC)                                                              \
  {                                                                                        \
    if (i + 1 < nsteps) {                                                                  \
      stage_aw(wA1, wA2, i + 1, ldsAw, cur ^ 1, coq, lane);                                \
      asm volatile("s_waitcnt vmcnt(4)" ::: "memory");                                     \
    } else {                                                                               \
      asm volatile("s_waitcnt vmcnt(0)" ::: "memory");                                     \
    }                                                                                      \
    bf16x8 af[4], bf[4];                                                                   \
    const char* lA = ldsAw + cur * 4096;                                                   \
    _Pragma("unroll")                                                                      \
    for (int f = 0; f < 4; ++f) af[f] = *(const bf16x8*)(lA + aOff[f]);                    \
    _Pragma("unroll")                                                                      \
    for (int f = 0; f < 4; ++f) {                                                          \
      int wp = wpb[f] + (WP_ADD);                                                          \
      bf[f] = *(const bf16x8*)(ldsB + wp * 256 + (((KC)*64 + q * 16) ^ ((wp & 7) << 4)));  \
    }                                                                                      \
    __builtin_amdgcn_s_setprio(1);                                                         \
    _Pragma("unroll")                                                                      \
    for (int fm = 0; fm < 4; ++fm)                                                         \
      _Pragma("unroll")                                                                    \
      for (int fn = 0; fn < 4; ++fn)                                                       \
        acc[fm][fn] =                                                                      \
            __builtin_amdgcn_mfma_f32_16x16x32_bf16(af[fm], bf[fn], acc[fm][fn], 0, 0, 0); \
    __builtin_amdgcn_s_setprio(0);                                                         \
    cur ^= 1;                                                                              \
    ++i;                                                                                   \
  }

__device__ __forceinline__ void conv_pipeline(const char* inB1, const char* inB2,
                                              const char* wA1, const char* wA2,
                                              int h, int nsteps, char* lds,
                                              f32x4 (&acc)[4][4]) {
  const int t = threadIdx.x;
  const int wv = t >> 6, lane = t & 63;
  const int lane15 = lane & 15, q = lane >> 4;
  const int coq = wv >> 1, wh = wv & 1;
  char* ldsB = lds;
  char* ldsAw = lds + 33280 + wv * 8192;   // per-wave 2x4KB ring

  int aOff[4];
#pragma unroll
  for (int f = 0; f < 4; ++f) {
    int ra = f * 16 + lane15;              // local row in the wave's 64-row half
    aOff[f] = ra * 64 + ((q ^ ((ra >> 1) & 3)) << 4);  // (coq*64+ra)>>1 &3 == (ra>>1)&3
  }
  int wpb[4];
#pragma unroll
  for (int f = 0; f < 4; ++f) wpb[f] = wh * 64 + f * 16 + lane15;

  // zero pad rows 0 (w=-1) and 129 (w=128) ONCE; stage_b only writes rows 1..128.
  {
    int4 z = {0, 0, 0, 0};
    if (t < 16) *(int4*)(ldsB + t * 16) = z;
    else if (t < 32) *(int4*)(ldsB + 33024 + (t - 16) * 16) = z;
  }

  stage_aw(wA1, wA2, 0, ldsAw, 0, coq, lane);   // prologue A(0)

  int cur = 0, i = 0;
  for (int outer = 0; outer < 6; ++outer) {
    const int half = (outer >= 3) ? 1 : 0;
    const int d = outer - half * 3;
    const int hs = h + d - 1;
    const char* plane = (hs >= 0 && hs < 128)
                            ? inB1 + (size_t)hs * 65536 + (size_t)half * 32768
                            : nullptr;
    asm volatile("s_waitcnt lgkmcnt(0)" ::: "memory");
    __builtin_amdgcn_s_barrier();          // release ldsB (all waves' reads done)
    stage_b(plane, ldsB, t);
    asm volatile("s_waitcnt vmcnt(0) lgkmcnt(0)" ::: "memory");
    __builtin_amdgcn_s_barrier();          // ldsB ready (each wave drained its slice)
#pragma unroll
    for (int dwi = 0; dwi < 3; ++dwi)
#pragma unroll
      for (int kc = 0; kc < 4; ++kc) CONV_STEP(dwi, kc)
  }
  if (nsteps > 72) {   // fused 1x1 (c1) segment: row h, dw=0 (wp = w+1)
    for (int half2 = 0; half2 < 2; ++half2) {
      asm volatile("s_waitcnt lgkmcnt(0)" ::: "memory");
      __builtin_amdgcn_s_barrier();
      stage_b(inB2 + (size_t)h * 65536 + (size_t)half2 * 32768, ldsB, t);
      asm volatile("s_waitcnt vmcnt(0) lgkmcnt(0)" ::: "memory");
      __builtin_amdgcn_s_barrier();
#pragma unroll
      for (int kc = 0; kc < 4; ++kc) CONV_STEP(1, kc)
    }
  }
}

// BN+ReLU, store to staging layout (8B = 4 co per lane); block covers co-half `cohalf`.
__device__ __forceinline__ void store_pad_relu(f32x4 (&acc)[4][4], const float* __restrict__ st,
                                               int cohalf, int b, int h, char* __restrict__ out) {
  const int t = threadIdx.x, lane = t & 63, wv = t >> 6;
  const int lane15 = lane & 15, q = lane >> 4, coq = wv >> 1, wh = wv & 1;
  char* plane = out + (size_t)(b * 128 + h) * 65536 + cohalf * 32768;
#pragma unroll
  for (int fm = 0; fm < 4; ++fm) {
    int co_l = coq * 64 + fm * 16 + q * 4;
    int co = cohalf * 128 + co_l;
    float ss[4], tt[4];
#pragma unroll
    for (int r = 0; r < 4; ++r) { ss[r] = st[co + r]; tt[r] = st[256 + co + r]; }
#pragma unroll
    for (int fn = 0; fn < 4; ++fn) {
      int w = wh * 64 + fn * 16 + lane15;
      short4 o;
      o.x = (short)f2bf(fmaxf(acc[fm][fn][0] * ss[0] + tt[0], 0.f));
      o.y = (short)f2bf(fmaxf(acc[fm][fn][1] * ss[1] + tt[1], 0.f));
      o.z = (short)f2bf(fmaxf(acc[fm][fn][2] * ss[2] + tt[2], 0.f));
      o.w = (short)f2bf(fmaxf(acc[fm][fn][3] * ss[3] + tt[3], 0.f));
      *(short4*)(plane + w * 256 + ((co_l * 2) ^ (((w + 1) & 7) << 4))) = o;
    }
  }
}

// ---------------- up conv: BN+ReLU then fused row-max over W ----------------
__global__ __launch_bounds__(256, 2) void conv_up_kernel(const char* __restrict__ xb,
                                                         const char* __restrict__ wp,
                                                         const float* __restrict__ st,
                                                         float* __restrict__ rmax) {
  __shared__ __align__(16) char lds[66048];
  int swz = (blockIdx.x & 7) * 64 + (blockIdx.x >> 3);
  int b = swz >> 7, h = swz & 127;
  int cohalf = blockIdx.y;
  const char* wA = wp + (size_t)cohalf * 589824;
  f32x4 acc[4][4];
  zero_acc(acc);
  conv_pipeline(xb + (size_t)b * 8388608, nullptr, wA, wA, h, 72, lds, acc);

  const int t = threadIdx.x, lane = t & 63, wv = t >> 6;
  const int lane15 = lane & 15, q = lane >> 4, coq = wv >> 1, wh = wv & 1;
  float* rlds = (float*)lds;
  __syncthreads();
#pragma unroll
  for (int fm = 0; fm < 4; ++fm) {
    int co_l = coq * 64 + fm * 16 + q * 4;
    int co = cohalf * 128 + co_l;
#pragma unroll
    for (int r = 0; r < 4; ++r) {
      float ss = st[co + r], tt = st[256 + co + r];
      float v = 0.f;   // ReLU floor
#pragma unroll
      for (int fn = 0; fn < 4; ++fn) v = fmaxf(v, acc[fm][fn][r] * ss + tt);
      v = fmaxf(v, __shfl_xor(v, 1));
      v = fmaxf(v, __shfl_xor(v, 2));
      v = fmaxf(v, __shfl_xor(v, 4));
      v = fmaxf(v, __shfl_xor(v, 8));
      if (lane15 == 0) rlds[wh * 128 + co_l + r] = v;
    }
  }
  __syncthreads();
  if (t < 128)
    rmax[(size_t)(b * 128 + h) * 256 + cohalf * 128 + t] = fmaxf(rlds[t], rlds[128 + t]);
}

// ---------------- down conv ----------------
__global__ __launch_bounds__(256, 2) void conv_down_kernel(const char* __restrict__ xb,
                                                           const char* __restrict__ wp,
                                                           const float* __restrict__ st,
                                                           char* __restrict__ out) {
  __shared__ __align__(16) char lds[66048];
  int swz = (blockIdx.x & 7) * 64 + (blockIdx.x >> 3);
  int b = swz >> 7, h = swz & 127;
  int cohalf = blockIdx.y;
  const char* wA = wp + (size_t)cohalf * 589824;
  f32x4 acc[4][4];
  zero_acc(acc);
  conv_pipeline(xb + (size_t)b * 8388608, nullptr, wA, wA, h, 72, lds, acc);
  store_pad_relu(acc, st, cohalf, b, h, out);
}

// ---------------- col max over H ----------------
__global__ __launch_bounds__(256) void colmax_kernel(const char* __restrict__ dp,
                                                     float* __restrict__ cmax) {
  int bw = blockIdx.x; int b = bw >> 7, w = bw & 127;
  int c = threadIdx.x;
  size_t base = (size_t)b * 8388608 + (size_t)(c >> 7) * 32768 + w * 256 +
                (((c & 127) * 2) ^ (((w + 1) & 7) << 4));
  float m = 0.f;
  for (int h = 0; h < 128; ++h) {
    u16 raw = *(const u16*)(dp + base + (size_t)h * 65536);
    m = fmaxf(m, __uint_as_float(((unsigned)raw) << 16));
  }
  cmax[(size_t)(b * 128 + w) * 256 + c] = m;
}

// ---------------- pooled = rmax[b,h,c] + cmax[b,w,c] (vectorized 16B stores) --------
// plane = 65,536 B = 4096 x 16B chunks: id = it*256 + t, it < 16.
// half = id>>11, w = (id&2047)>>4, slot = id&15; c0 = half*128 + slot*8;
// swizzled byte-in-row = (slot ^ ((w+1)&7)) << 4  (key XORs bits 4..6 only).
__global__ __launch_bounds__(256) void pooled_kernel(const float* __restrict__ rmax,
                                                     const float* __restrict__ cmax,
                                                     char* __restrict__ dp) {
  int bh = blockIdx.x; int b = bh >> 7, h = bh & 127;
  int t = threadIdx.x;
  char* plane = dp + (size_t)(b * 128 + h) * 65536;
  const float* rm = rmax + (size_t)(b * 128 + h) * 256;
#pragma unroll
  for (int it = 0; it < 16; ++it) {
    int id = it * 256 + t;                 // 0..4095 chunk of 16B
    int half = id >> 11, rem = id & 2047;
    int w = rem >> 4, slot = rem & 15;
    int c0 = half * 128 + slot * 8;
    const float* cm = cmax + (size_t)(b * 128 + w) * 256 + c0;
    const float* rr = rm + c0;
    u16 e[8];
#pragma unroll
    for (int k = 0; k < 8; ++k) e[k] = f2bf(rr[k] + cm[k]);
    int4 v;
    v.x = (int)(e[0] | ((unsigned)e[1] << 16));
    v.y = (int)(e[2] | ((unsigned)e[3] << 16));
    v.z = (int)(e[4] | ((unsigned)e[5] << 16));
    v.w = (int)(e[6] | ((unsigned)e[7] << 16));
    *(int4*)(plane + half * 32768 + w * 256 + ((slot ^ ((w + 1) & 7)) << 4)) = v;
  }
}

// ---------------- merge conv (pooled 3x3) + fused c1 (1x1 on xb) ----------------
__global__ __launch_bounds__(256, 2) void conv_merge_kernel(const char* __restrict__ dp,
                                                            const char* __restrict__ xb,
                                                            const char* __restrict__ wp_p,
                                                            const char* __restrict__ wp_c1,
                                                            const float* __restrict__ st,
                                                            char* __restrict__ out) {
  __shared__ __align__(16) char lds[66048];
  int swz = (blockIdx.x & 7) * 64 + (blockIdx.x >> 3);
  int b = swz >> 7, h = swz & 127;
  int cohalf = blockIdx.y;
  f32x4 acc[4][4];
  zero_acc(acc);
  conv_pipeline(dp + (size_t)b * 8388608, xb + (size_t)b * 8388608,
                wp_p + (size_t)cohalf * 589824, wp_c1 + (size_t)cohalf * 65536,
                h, 80, lds, acc);
  store_pad_relu(acc, st, cohalf, b, h, out);
}

// ---------------- final conv c2: BN+ReLU, NCHW fp32 out via LDS transpose ----------------
__global__ __launch_bounds__(256, 2) void conv_c2_kernel(const char* __restrict__ relu1,
                                                         const char* __restrict__ wp,
                                                         const float* __restrict__ st,
                                                         float* __restrict__ out) {
  __shared__ __align__(16) char lds[66048];
  int swz = (blockIdx.x & 7) * 64 + (blockIdx.x >> 3);
  int b = swz >> 7, h = swz & 127;
  int cohalf = blockIdx.y;
  const char* wA = wp + (size_t)cohalf * 589824;
  f32x4 acc[4][4];
  zero_acc(acc);
  conv_pipeline(relu1 + (size_t)b * 8388608, nullptr, wA, wA, h, 72, lds, acc);

  const int t = threadIdx.x, lane = t & 63, wv = t >> 6;
  const int lane15 = lane & 15, q = lane >> 4, coq = wv >> 1, wh = wv & 1;
  float* tl = (float*)lds;   // [16][132]
  for (int g = 0; g < 8; ++g) {
    __syncthreads();
    if (coq == (g >> 2)) {
      int fm = g & 3;
      int co_l = coq * 64 + fm * 16 + q * 4;
      int co = cohalf * 128 + co_l;
#pragma unroll
      for (int r = 0; r < 4; ++r) {
        float ss = st[co + r], tt = st[256 + co + r];
#pragma unroll
        for (int fn = 0; fn < 4; ++fn) {
          int w = wh * 64 + fn * 16 + lane15;
          tl[(q * 4 + r) * 132 + w] = fmaxf(acc[fm][fn][r] * ss + tt, 0.f);
        }
      }
    }
    __syncthreads();
    int row = t >> 4, ch = t & 15;
    int co = cohalf * 128 + g * 16 + row;
    float* dst = out + (size_t)((b * 256 + co) * 128 + h) * 128 + ch * 8;
    float4 p0 = *(float4*)&tl[row * 132 + ch * 8];
    float4 p1 = *(float4*)&tl[row * 132 + ch * 8 + 4];
    *(float4*)dst = p0;
    *(float4*)(dst + 4) = p1;
  }
}

extern "C" void kernel_launch(void* const* d_in, const int* in_sizes, int n_in,
                              void* d_out, int out_size, void* d_ws, size_t ws_size,
                              hipStream_t stream) {
  (void)in_sizes; (void)n_in; (void)out_size; (void)ws_size;
  const float* x    = (const float*)d_in[0];
  const float* w_up = (const float*)d_in[1];
  const float* w_dn = (const float*)d_in[6];
  const float* w_p  = (const float*)d_in[11];
  const float* w_c1 = (const float*)d_in[16];
  const float* w_c2 = (const float*)d_in[21];

  // ws layout (bytes) — total 106,571,776
  char* ws = (char*)d_ws;
  char* xb    = ws;                         // 33,554,432 (32MB staging layout)
  char* dp    = ws + 33554432ull;           // 33,554,432 (down, then pooled)
  char* relu1 = ws + 67108864ull;           // 33,554,432
  char* wp_up = ws + 100663296ull;          // 1,179,648
  char* wp_dn = ws + 101842944ull;          // 1,179,648
  char* wp_p  = ws + 103022592ull;          // 1,179,648
  char* wp_c2 = ws + 104202240ull;          // 1,179,648
  char* wp_c1 = ws + 105381888ull;          // 131,072
  float* st   = (float*)(ws + 105512960ull);// 10,240
  float* rmax = (float*)(ws + 105523200ull);// 524,288
  float* cmax = (float*)(ws + 106047488ull);// 524,288

  bn_prep_kernel<<<1, 256, 0, stream>>>((const float*)d_in[2], (const float*)d_in[3],
                                        (const float*)d_in[4], (const float*)d_in[5], st);
  bn_prep_kernel<<<1, 256, 0, stream>>>((const float*)d_in[7], (const float*)d_in[8],
                                        (const float*)d_in[9], (const float*)d_in[10], st + 512);
  bn_prep_kernel<<<1, 256, 0, stream>>>((const float*)d_in[12], (const float*)d_in[13],
                                        (const float*)d_in[14], (const float*)d_in[15], st + 1024);
  bn_prep_kernel<<<1, 256, 0, stream>>>((const float*)d_in[17], (const float*)d_in[18],
                                        (const float*)d_in[19], (const float*)d_in[20], st + 1536);
  bn_prep_kernel<<<1, 256, 0, stream>>>((const float*)d_in[22], (const float*)d_in[23],
                                        (const float*)d_in[24], (const float*)d_in[25], st + 2048);
  bn_fix_kernel<<<1, 256, 0, stream>>>(st);

  wprep3_kernel<<<2304, 256, 0, stream>>>(w_up, (u16*)wp_up);
  wprep3_kernel<<<2304, 256, 0, stream>>>(w_dn, (u16*)wp_dn);
  wprep3_kernel<<<2304, 256, 0, stream>>>(w_p, (u16*)wp_p);
  wprep3_kernel<<<2304, 256, 0, stream>>>(w_c2, (u16*)wp_c2);
  wprep1_kernel<<<256, 256, 0, stream>>>(w_c1, (u16*)wp_c1, st + 1536);

  nchw_to_nhwc_kernel<<<512, 256, 0, stream>>>(x, xb);

  conv_up_kernel<<<dim3(512, 2), 256, 0, stream>>>(xb, wp_up, st, rmax);
  conv_down_kernel<<<dim3(512, 2), 256, 0, stream>>>(xb, wp_dn, st + 512, dp);
  colmax_kernel<<<512, 256, 0, stream>>>(dp, cmax);
  pooled_kernel<<<512, 256, 0, stream>>>(rmax, cmax, dp);
  conv_merge_kernel<<<dim3(512, 2), 256, 0, stream>>>(dp, xb, wp_p, wp_c1, st + 1024, relu1);
  conv_c2_kernel<<<dim3(512, 2), 256, 0, stream>>>(relu1, wp_c2, st + 2048, (float*)d_out);
}